// Round 10
// baseline (296.927 us; speedup 1.0000x reference)
//
#include <hip/hip_runtime.h>
#include <hip/hip_bf16.h>

#define DEV static __device__ __forceinline__

typedef __attribute__((ext_vector_type(8))) short bf16x8;
typedef __attribute__((ext_vector_type(4))) float f32x4;

constexpr int Bb  = 2;
constexpr int Ss  = 2048;
constexpr int Dd  = 1024;
constexpr int Hh  = 16;
constexpr int DHh = 64;
constexpr int Mm  = Bb * Ss;    // 4096 rows
constexpr int Kk  = Dd;         // 1024
constexpr int Nn  = Hh * DHh;   // 1024

DEV ushort f2bf(float x) {
    union { float f; unsigned u; } v; v.f = x;
    unsigned r = v.u + 0x7FFFu + ((v.u >> 16) & 1u);
    return (ushort)(r >> 16);
}

DEV void block_barrier() {
    asm volatile("" ::: "memory");
    __builtin_amdgcn_s_barrier();
    asm volatile("" ::: "memory");
}

// ---------------------------------------------------------------------------
// 1) fp32 -> bf16 convert (vectorized), 3 arrays in one launch via blockIdx.y
// ---------------------------------------------------------------------------
struct CvtArgs { const float* src[3]; ushort* dst[3]; };

__global__ void cvt_kernel(CvtArgs a) {
    int which = blockIdx.y;
    const float* __restrict__ s = a.src[which];
    ushort* __restrict__ d = a.dst[which];
    int i = (blockIdx.x * 256 + threadIdx.x) * 4;
    float4 v = *(const float4*)(s + i);
    ushort4 o;
    o.x = f2bf(v.x); o.y = f2bf(v.y); o.z = f2bf(v.z); o.w = f2bf(v.w);
    *(ushort4*)(d + i) = o;
}

// ---------------------------------------------------------------------------
// 2) weight transpose+convert: src[h][R][C] f32 -> dst[h][C][R] bf16
//    (B^T layout: row n, k-contiguous).  All 4 weights in ONE launch:
//    grid (256, 4); y in {0,1,2} = W_Q/K/V (R=1024,C=64, h=bid/16),
//    y=3 = W_O (R=C=1024, h degenerates to 0; 256 tiles cover the matrix).
// ---------------------------------------------------------------------------
struct WtArgs { const float* src[4]; ushort* dst[4]; int R[4]; int C[4]; };

__global__ void wtrans_kernel(WtArgs a) {
    int which = blockIdx.y;
    const float* __restrict__ src = a.src[which];
    ushort* __restrict__ dst = a.dst[which];
    int R = a.R[which], C = a.C[which];
    int ntr = R >> 6, ntc = C >> 6;
    int bid = blockIdx.x;
    int h  = bid / (ntr * ntc);
    int rr = bid % (ntr * ntc);
    int rt = rr / ntc, ct = rr % ntc;
    const float* sp = src + (size_t)h * R * C;
    ushort*      dp = dst + (size_t)h * R * C;
    __shared__ float tile[64][65];
    int tid = threadIdx.x;
#pragma unroll
    for (int i = 0; i < 16; i++) {
        int f = tid + i * 256;
        int r = f >> 6, c = f & 63;
        tile[r][c] = sp[(size_t)(rt * 64 + r) * C + ct * 64 + c];
    }
    __syncthreads();
#pragma unroll
    for (int i = 0; i < 16; i++) {
        int f = tid + i * 256;
        int c = f >> 6, r = f & 63;
        dp[(size_t)(ct * 64 + c) * R + rt * 64 + r] = f2bf(tile[r][c]);
    }
}

// ---------------------------------------------------------------------------
// 3) GEMM: C[M=4096][N=1024] = A[M][K=1024] * B (+bias), A row-major bf16,
//    BT row-major [n][k] bf16.  128x128 tile, BK=32, 4 waves (2x2), each wave
//    computes 64x64 via 4x4 grid of 16x16x32 MFMA tiles.
//    3-buffer LDS pipeline, global_load_lds width 16, counted vmcnt.
//    MODE 0: out bf16 in [B,H,S,DH] (+bias[n]);  MODE 1: out f32 row-major.
// ---------------------------------------------------------------------------
struct Gemm3 { const ushort* A[3]; const ushort* BT[3]; const float* bias[3]; void* out[3]; };

template<int MODE>
__global__ void gemm_kernel(Gemm3 g) {
    constexpr int BK = 32;
    constexpr int NT = Kk / BK;   // 32
    int which = blockIdx.y;
    const ushort* __restrict__ A    = g.A[which];
    const ushort* __restrict__ BT   = g.BT[which];
    const float*  __restrict__ bias = g.bias[which];

    __shared__ ushort As[3][128 * BK];
    __shared__ ushort Bs[3][128 * BK];

    int tid = threadIdx.x;
    int w = tid >> 6, lane = tid & 63;
    int mt = blockIdx.x >> 3, nt = blockIdx.x & 7;
    int m0 = mt * 128, n0 = nt * 128;

    auto stage = [&](int buf, int t) {
        int k0 = t * BK;
#pragma unroll
        for (int c = 0; c < 2; c++) {
            int q = w * 2 + c;
            int idx = q * 64 + lane;
            int r = idx >> 2, kc = idx & 3;
            const ushort* ga = A  + (size_t)(m0 + r) * Kk + k0 + kc * 8;
            const ushort* gb = BT + (size_t)(n0 + r) * Kk + k0 + kc * 8;
            __builtin_amdgcn_global_load_lds(
                (const __attribute__((address_space(1))) unsigned int*)ga,
                (__attribute__((address_space(3))) unsigned int*)(&As[buf][q * 512]), 16, 0, 0);
            __builtin_amdgcn_global_load_lds(
                (const __attribute__((address_space(1))) unsigned int*)gb,
                (__attribute__((address_space(3))) unsigned int*)(&Bs[buf][q * 512]), 16, 0, 0);
        }
    };

    const f32x4 Z4 = {0.f, 0.f, 0.f, 0.f};
    f32x4 acc[4][4];
#pragma unroll
    for (int a = 0; a < 4; a++)
#pragma unroll
        for (int b = 0; b < 4; b++) acc[a][b] = Z4;

    int mb = (w >> 1) * 64, nb = (w & 1) * 64;
    int rofs = lane & 15, kofs = (lane >> 4) * 8;

    stage(0, 0);
    stage(1, 1);
    for (int t = 0; t < NT; t++) {
        if (t < NT - 1) asm volatile("s_waitcnt vmcnt(4)" ::: "memory");
        else            asm volatile("s_waitcnt vmcnt(0)" ::: "memory");
        block_barrier();
        int buf = t % 3;
        bf16x8 fa[4], fb[4];
#pragma unroll
        for (int a = 0; a < 4; a++)
            fa[a] = *(const bf16x8*)&As[buf][(mb + 16 * a + rofs) * BK + kofs];
#pragma unroll
        for (int b = 0; b < 4; b++)
            fb[b] = *(const bf16x8*)&Bs[buf][(nb + 16 * b + rofs) * BK + kofs];
#pragma unroll
        for (int a = 0; a < 4; a++)
#pragma unroll
            for (int b = 0; b < 4; b++)
                acc[a][b] = __builtin_amdgcn_mfma_f32_16x16x32_bf16(fa[a], fb[b], acc[a][b], 0, 0, 0);
        if (t + 2 < NT) stage((t + 2) % 3, t + 2);
    }

    // epilogue: C/D layout col=lane&15, row=4*(lane>>4)+i   [guide-verified]
#pragma unroll
    for (int b = 0; b < 4; b++) {
        int col = n0 + nb + 16 * b + (lane & 15);
        float bv = bias[col];
#pragma unroll
        for (int a = 0; a < 4; a++) {
            f32x4 v = acc[a][b];
#pragma unroll
            for (int i = 0; i < 4; i++) {
                int row = m0 + mb + 16 * a + 4 * (lane >> 4) + i;
                float x = v[i] + bv;
                if constexpr (MODE == 0) {
                    ushort* o = (ushort*)g.out[which];
                    int bb = row >> 11, s = row & (Ss - 1);
                    int h = col >> 6, e = col & 63;
                    o[((((size_t)bb * Hh + h) * Ss + s) << 6) + e] = f2bf(x);
                } else {
                    float* o = (float*)g.out[which];
                    o[(size_t)row * Nn + col] = x;
                }
            }
        }
    }
}

// ---------------------------------------------------------------------------
// 4) causal flash attention, bf16 MFMA.
//    grid = (B*H)*32 q-tiles; 256 threads = 4 waves; wave w owns 16 Q rows.
//    LPT dispatch: qt = 31 - (blockIdx.x & 31)  — heavy (long-loop) tiles
//    first, light tiles fill the scheduling tail.  Same-bh blocks remain
//    consecutive, so K/V L2 sharing is unchanged.
//    K tile row-major LDS [64][72]; V tile transposed pair-packed u32 with
//    combined XOR swizzle gs = gg ^ (e&7) ^ ((e>>3)&7)  — conflict-free on
//    BOTH the u32 store side and the ds_read_b128 PV-fragment side
//    (2 accesses/bank/quarter-wave, uniform).  P round-trips per-wave LDS.
// ---------------------------------------------------------------------------
__global__ void attn_kernel(const ushort* __restrict__ qp, const ushort* __restrict__ kp,
                            const ushort* __restrict__ vp, ushort* __restrict__ zb) {
    int bh = blockIdx.x >> 5;
    int qt = 31 - ((int)blockIdx.x & 31);   // LPT: longest job first
    int q0 = qt * 64;
    int tid = threadIdx.x, w = tid >> 6, lane = tid & 63;
    int l15 = lane & 15, l4 = lane >> 4;

    __shared__ ushort   Ks[64 * 72];
    __shared__ unsigned Vt[64 * 32];
    __shared__ ushort   Ps[4][16 * 72];

    const size_t base = (size_t)bh * Ss * 64;

    bf16x8 fq[2];
    {
        const ushort* qr = qp + base + (size_t)(q0 + 16 * w + l15) * 64;
        fq[0] = *(const bf16x8*)(qr + l4 * 8);
        fq[1] = *(const bf16x8*)(qr + 32 + l4 * 8);
    }

    const f32x4 Z4 = {0.f, 0.f, 0.f, 0.f};
    float m_[4], l_[4];
    f32x4 o[4];
#pragma unroll
    for (int i = 0; i < 4; i++) { m_[i] = -1e30f; l_[i] = 0.f; }
#pragma unroll
    for (int e = 0; e < 4; e++) o[e] = Z4;

    for (int t = 0; t <= qt; t++) {
        int k0 = t * 64;
        // stage K: [row][e] row-major, pad 72
#pragma unroll
        for (int c = 0; c < 2; c++) {
            int f = tid + c * 256;
            int row = f >> 3, e0 = (f & 7) * 8;
            *(uint4*)&Ks[row * 72 + e0] =
                *(const uint4*)(kp + base + (size_t)(k0 + row) * 64 + e0);
        }
        // stage V: transposed (Vt[e][c-pair] u32 = {V[c][e], V[c+1][e]}),
        // combined XOR swizzle (store side: e&7 == j inside the loop)
        {
            int c2 = tid >> 3;            // pair index 0..31
            int e0 = (tid & 7) * 8;
            const ushort* v0 = vp + base + (size_t)(k0 + 2 * c2) * 64 + e0;
            uint4 ua = *(const uint4*)v0;
            uint4 ub = *(const uint4*)(v0 + 64);
            const ushort* pa = (const ushort*)&ua;
            const ushort* pb = (const ushort*)&ub;
            int gg = c2 >> 2, cl = c2 & 3;
#pragma unroll
            for (int j = 0; j < 8; j++) {
                int e = e0 + j;
                int gs = gg ^ (e & 7) ^ ((e >> 3) & 7);
                Vt[e * 32 + gs * 4 + cl] = (unsigned)pa[j] | ((unsigned)pb[j] << 16);
            }
        }
        __syncthreads();

        // QK^T : A=Q (rows l15, k contiguous), B=K rows as B^T
        f32x4 s[4];
#pragma unroll
        for (int ct = 0; ct < 4; ct++) {
            s[ct] = Z4;
#pragma unroll
            for (int ks = 0; ks < 2; ks++) {
                bf16x8 fk = *(const bf16x8*)&Ks[(16 * ct + l15) * 72 + 32 * ks + l4 * 8];
                s[ct] = __builtin_amdgcn_mfma_f32_16x16x32_bf16(fq[ks], fk, s[ct], 0, 0, 0);
            }
        }
        // scale + causal mask (diagonal tile only)
#pragma unroll
        for (int ct = 0; ct < 4; ct++)
#pragma unroll
            for (int i = 0; i < 4; i++)
                s[ct][i] *= 0.125f;
        if (t == qt) {
#pragma unroll
            for (int ct = 0; ct < 4; ct++) {
                int cg = k0 + 16 * ct + l15;
#pragma unroll
                for (int i = 0; i < 4; i++) {
                    int rg = q0 + 16 * w + 4 * l4 + i;
                    if (cg > rg) s[ct][i] = -1e30f;
                }
            }
        }
        // online softmax: each q-row's 64 scores live in the 16 lanes of one
        // l4 group, indexed by (ct, l15); rows per lane: 4*l4 + i
        float tm[4];
#pragma unroll
        for (int i = 0; i < 4; i++)
            tm[i] = fmaxf(fmaxf(s[0][i], s[1][i]), fmaxf(s[2][i], s[3][i]));
#pragma unroll
        for (int d = 1; d < 16; d <<= 1)
#pragma unroll
            for (int i = 0; i < 4; i++)
                tm[i] = fmaxf(tm[i], __shfl_xor(tm[i], d));
        float alpha[4], rs[4];
#pragma unroll
        for (int i = 0; i < 4; i++) {
            float mn = fmaxf(m_[i], tm[i]);
            alpha[i] = __expf(m_[i] - mn);
            m_[i] = mn;
            rs[i] = 0.f;
        }
#pragma unroll
        for (int ct = 0; ct < 4; ct++)
#pragma unroll
            for (int i = 0; i < 4; i++) {
                float p = __expf(s[ct][i] - m_[i]);
                s[ct][i] = p;
                rs[i] += p;
            }
#pragma unroll
        for (int d = 1; d < 16; d <<= 1)
#pragma unroll
            for (int i = 0; i < 4; i++)
                rs[i] += __shfl_xor(rs[i], d);
#pragma unroll
        for (int i = 0; i < 4; i++)
            l_[i] = l_[i] * alpha[i] + rs[i];
        // P -> LDS (C/D layout in, A layout out; per-wave private)
#pragma unroll
        for (int ct = 0; ct < 4; ct++)
#pragma unroll
            for (int i = 0; i < 4; i++)
                Ps[w][(4 * l4 + i) * 72 + 16 * ct + l15] = f2bf(s[ct][i]);
        // rescale O
#pragma unroll
        for (int e = 0; e < 4; e++)
#pragma unroll
            for (int i = 0; i < 4; i++)
                o[e][i] *= alpha[i];
        // PV : A=P (rows l15), B=V via packed-transposed swizzled Vt
#pragma unroll
        for (int ks = 0; ks < 2; ks++) {
            bf16x8 fp = *(const bf16x8*)&Ps[w][l15 * 72 + 32 * ks + l4 * 8];
#pragma unroll
            for (int et = 0; et < 4; et++) {
                int e = 16 * et + l15;
                int gg = 4 * ks + l4;
                int gs = gg ^ (e & 7) ^ ((e >> 3) & 7);
                bf16x8 fv = *(const bf16x8*)&Vt[e * 32 + gs * 4];
                o[et] = __builtin_amdgcn_mfma_f32_16x16x32_bf16(fp, fv, o[et], 0, 0, 0);
            }
        }
        __syncthreads();
    }

    // epilogue: z[b][s][h*64+e] bf16
    int b = bh >> 4, h = bh & 15;
#pragma unroll
    for (int i = 0; i < 4; i++) {
        float inv = 1.f / l_[i];
        int rg = q0 + 16 * w + 4 * l4 + i;
        ushort* zr = zb + ((size_t)b * Ss + rg) * 1024 + h * 64;
#pragma unroll
        for (int et = 0; et < 4; et++)
            zr[16 * et + l15] = f2bf(o[et][i] * inv);
    }
}

// ---------------------------------------------------------------------------
// launcher — workspace plan (bf16 elems), 56 MB total:
//   [0:4M)   xq   (aliased by zbf after QKV GEMM — xq is dead by then)
//   [4M:8M)  xk
//   [8M:12M) xv
//   [12M:13M) wqT  [13M:14M) wkT  [14M:15M) wvT  [15M:16M) woT
//   [16M:20M) qp  [20M:24M) kp2  [24M:28M) vp2
// If ws_size is too small, launch nothing (validation will fail loudly
// instead of faulting the container).
// ---------------------------------------------------------------------------
extern "C" void kernel_launch(void* const* d_in, const int* in_sizes, int n_in,
                              void* d_out, int out_size, void* d_ws, size_t ws_size,
                              hipStream_t stream) {
    (void)in_sizes; (void)n_in; (void)out_size;
    const float* Xq = (const float*)d_in[0];
    const float* Xk = (const float*)d_in[1];
    const float* Xv = (const float*)d_in[2];
    const float* Wq = (const float*)d_in[3];
    const float* Wk = (const float*)d_in[4];
    const float* Wv = (const float*)d_in[5];
    const float* Wo = (const float*)d_in[6];
    const float* bq = (const float*)d_in[7];
    const float* bk = (const float*)d_in[8];
    const float* bv = (const float*)d_in[9];
    const float* bo = (const float*)d_in[10];
    float* out = (float*)d_out;

    const size_t MD = (size_t)Mm * Dd;   // 4M elems
    const size_t WD = (size_t)Dd * Nn;   // 1M elems per weight
    const size_t need_elems = 3 * MD + 4 * WD + 3 * MD;  // 28M ushorts = 56 MB
    if (ws_size < need_elems * sizeof(ushort)) return;   // defensive: no OOB faults

    ushort* ws = (ushort*)d_ws;
    ushort* xq  = ws;
    ushort* xk  = xq  + MD;
    ushort* xv  = xk  + MD;
    ushort* wqT = xv  + MD;
    ushort* wkT = wqT + WD;
    ushort* wvT = wkT + WD;
    ushort* woT = wvT + WD;
    ushort* qp  = woT + WD;
    ushort* kp2 = qp  + MD;
    ushort* vp2 = kp2 + MD;
    ushort* zbf = xq;          // alias: xq dead after QKV GEMM

    {
        CvtArgs a;
        a.src[0] = Xq; a.src[1] = Xk; a.src[2] = Xv;
        a.dst[0] = xq; a.dst[1] = xk; a.dst[2] = xv;
        cvt_kernel<<<dim3((Mm * Dd) / 1024, 3), dim3(256), 0, stream>>>(a);
    }
    {
        WtArgs a;
        a.src[0] = Wq;  a.src[1] = Wk;  a.src[2] = Wv;  a.src[3] = Wo;
        a.dst[0] = wqT; a.dst[1] = wkT; a.dst[2] = wvT; a.dst[3] = woT;
        a.R[0] = a.R[1] = a.R[2] = a.R[3] = 1024;
        a.C[0] = a.C[1] = a.C[2] = 64;   a.C[3] = 1024;
        wtrans_kernel<<<dim3(256, 4), dim3(256), 0, stream>>>(a);
    }
    {
        Gemm3 g;
        g.A[0] = xq;  g.A[1] = xk;  g.A[2] = xv;
        g.BT[0] = wqT; g.BT[1] = wkT; g.BT[2] = wvT;
        g.bias[0] = bq; g.bias[1] = bk; g.bias[2] = bv;
        g.out[0] = qp; g.out[1] = kp2; g.out[2] = vp2;
        gemm_kernel<0><<<dim3(256, 3), dim3(256), 0, stream>>>(g);
    }
    attn_kernel<<<dim3(1024), dim3(256), 0, stream>>>(qp, kp2, vp2, zbf);
    {
        Gemm3 g;
        g.A[0] = g.A[1] = g.A[2] = zbf;
        g.BT[0] = g.BT[1] = g.BT[2] = woT;
        g.bias[0] = g.bias[1] = g.bias[2] = bo;
        g.out[0] = g.out[1] = g.out[2] = out;
        gemm_kernel<1><<<dim3(256, 1), dim3(256), 0, stream>>>(g);
    }
}